// Round 9
// baseline (209.149 us; speedup 1.0000x reference)
//
#include <hip/hip_runtime.h>
#include <hip/hip_bf16.h>

// ---------- types ----------
typedef __attribute__((ext_vector_type(8))) short bf16x8;
typedef __attribute__((ext_vector_type(4))) float f32x4;
typedef __attribute__((ext_vector_type(16))) float f32x16;
typedef __attribute__((ext_vector_type(4))) unsigned u32x4;

#define DEVINL static __device__ __forceinline__
#define GLOBAL_AS __attribute__((address_space(1)))
#define LDS_AS __attribute__((address_space(3)))

DEVINL short f2b(float f) {
  __hip_bfloat16 h = __float2bfloat16(f);
  return __builtin_bit_cast(short, h);
}
DEVINL float b2f(short s) {
  return __bfloat162float(__builtin_bit_cast(__hip_bfloat16, s));
}
// packed f32->bf16 (RNE) : low = a, high = b. One VALU inst.
DEVINL unsigned pack2(float a, float b) {
  unsigned r;
  asm("v_cvt_pk_bf16_f32 %0, %1, %2" : "=v"(r) : "v"(a), "v"(b));
  return r;
}
// dst.hi(lanes 32-63) <-> src.lo(lanes 0-31) exchange, pure VALU
DEVINL void swap32(unsigned& x, unsigned& y) {
  asm("v_permlane32_swap_b32 %0, %1" : "+v"(x), "+v"(y));
}
// v + (v from lane^32); opaque mov keeps asm operands in distinct registers
DEVINL float xhalfsum(float v) {
  float t;
  asm("v_mov_b32 %0, %1" : "=v"(t) : "v"(v));
  asm("v_permlane32_swap_b32 %0, %1" : "+v"(v), "+v"(t));
  return v + t;
}
// raw hardware exp2 (1 transcendental inst; handles -1e30 -> 0 underflow)
DEVINL float exp2r(float x) {
  float r;
  asm("v_exp_f32 %0, %1" : "=v"(r) : "v"(x));
  return r;
}
DEVINL void load_lds16(const void* g, void* l) {
  __builtin_amdgcn_global_load_lds((const GLOBAL_AS void*)g, (LDS_AS void*)l, 16, 0, 0);
}
DEVINL void barrier_raw() {
  __builtin_amdgcn_sched_barrier(0);
  __builtin_amdgcn_s_barrier();
  __builtin_amdgcn_sched_barrier(0);
}
DEVINL f32x16 mfma32(bf16x8 a, bf16x8 b, f32x16 c) {
  return __builtin_amdgcn_mfma_f32_32x32x16_bf16(a, b, c, 0, 0, 0);
}
DEVINL f32x16 zero16() {
  f32x16 z;
#pragma unroll
  for (int i = 0; i < 16; ++i) z[i] = 0.f;
  return z;
}

// ---------- fused fp32 -> bf16 conversion (x, Wq, Wk, Wv, Wo in one launch) ----------
__global__ __launch_bounds__(256) void cvt_all_kernel(const float* __restrict__ x,
                                                      const float* __restrict__ wq,
                                                      const float* __restrict__ wk,
                                                      const float* __restrict__ wv,
                                                      const float* __restrict__ wo,
                                                      short* __restrict__ xb,
                                                      short* __restrict__ wcat,
                                                      short* __restrict__ wob) {
  int i = blockIdx.x * blockDim.x + threadIdx.x;
  if (i >= 2162688) return;
  const float* src;
  short* dst;
  if (i < 1048576) {
    src = x + (size_t)i * 8;
    dst = xb + (size_t)i * 8;
  } else if (i < 1572864) {
    int j = i - 1048576;
    src = wq + (size_t)j * 8;
    dst = wcat + (size_t)j * 8;
  } else if (i < 1605632) {
    int j = i - 1572864;
    src = wk + (size_t)j * 8;
    dst = wcat + 4194304 + (size_t)j * 8;
  } else if (i < 1638400) {
    int j = i - 1605632;
    src = wv + (size_t)j * 8;
    dst = wcat + 4456448 + (size_t)j * 8;
  } else {
    int j = i - 1638400;
    src = wo + (size_t)j * 8;
    dst = wob + (size_t)j * 8;
  }
  const float4* p = reinterpret_cast<const float4*>(src);
  float4 a = p[0], b = p[1];
  bf16x8 v;
  v[0] = f2b(a.x); v[1] = f2b(a.y); v[2] = f2b(a.z); v[3] = f2b(a.w);
  v[4] = f2b(b.x); v[5] = f2b(b.y); v[6] = f2b(b.z); v[7] = f2b(b.w);
  *reinterpret_cast<bf16x8*>(dst) = v;
}

// ---------- NT GEMM: C[m][n] = sum_k A[m][k]*B[n][k], A [M][K], B [N][K] bf16 ----------
template <int BF16OUT>
__global__ __launch_bounds__(256) void gemm_nt(const short* __restrict__ A,
                                               const short* __restrict__ B,
                                               void* __restrict__ Cv, int M, int N, int K) {
  __shared__ short As[128 * 64];
  __shared__ short Bs[128 * 64];
  const int tid = threadIdx.x;
  const int lane = tid & 63;
  const int wid = tid >> 6;
  const int lr = lane & 15, lg = lane >> 4;
  const int nwg = gridDim.x, cpx = nwg >> 3;
  const int lid = blockIdx.x;
  const int swz = (lid & 7) * cpx + (lid >> 3);
  const int nbn = N >> 7;
  const int bn = swz % nbn, bm = swz / nbn;
  const int wr = wid >> 1, wc = wid & 1;

  f32x4 acc[4][4];
#pragma unroll
  for (int i = 0; i < 4; ++i)
#pragma unroll
    for (int j = 0; j < 4; ++j) acc[i][j] = f32x4{0.f, 0.f, 0.f, 0.f};

  const short* Ag[4];
  const short* Bg[4];
#pragma unroll
  for (int j = 0; j < 4; ++j) {
    int o = j * 4096 + tid * 16;
    int row = o >> 7;
    int src = o ^ ((row & 7) << 4);
    int col = (src & 127) >> 1;
    Ag[j] = A + (size_t)(bm * 128 + row) * K + col;
    Bg[j] = B + (size_t)(bn * 128 + row) * K + col;
  }
  char* Asb = (char*)As;
  char* Bsb = (char*)Bs;
  const int lds_w = wid * 1024;

  for (int kt = 0; kt < K; kt += 64) {
    __syncthreads();
#pragma unroll
    for (int j = 0; j < 4; ++j) load_lds16(Ag[j] + kt, Asb + j * 4096 + lds_w);
#pragma unroll
    for (int j = 0; j < 4; ++j) load_lds16(Bg[j] + kt, Bsb + j * 4096 + lds_w);
    __syncthreads();

#pragma unroll
    for (int kc = 0; kc < 2; ++kc) {
      bf16x8 af[4], bfr[4];
#pragma unroll
      for (int mf = 0; mf < 4; ++mf) {
        int row = wr * 64 + mf * 16 + lr;
        int a_ = (row * 128 + kc * 64 + lg * 16) ^ ((row & 7) << 4);
        af[mf] = *(const bf16x8*)(Asb + a_);
      }
#pragma unroll
      for (int nf = 0; nf < 4; ++nf) {
        int row = wc * 64 + nf * 16 + lr;
        int a_ = (row * 128 + kc * 64 + lg * 16) ^ ((row & 7) << 4);
        bfr[nf] = *(const bf16x8*)(Bsb + a_);
      }
#pragma unroll
      for (int mf = 0; mf < 4; ++mf)
#pragma unroll
        for (int nf = 0; nf < 4; ++nf)
          acc[mf][nf] =
              __builtin_amdgcn_mfma_f32_16x16x32_bf16(af[mf], bfr[nf], acc[mf][nf], 0, 0, 0);
    }
  }

#pragma unroll
  for (int mf = 0; mf < 4; ++mf)
#pragma unroll
    for (int nf = 0; nf < 4; ++nf)
#pragma unroll
      for (int j = 0; j < 4; ++j) {
        int row = bm * 128 + wr * 64 + mf * 16 + lg * 4 + j;
        int col = bn * 128 + wc * 64 + nf * 16 + lr;
        if constexpr (BF16OUT)
          ((short*)Cv)[(size_t)row * N + col] = f2b(acc[mf][nf][j]);
        else
          ((float*)Cv)[(size_t)row * N + col] = acc[mf][nf][j];
      }
}

// ---------- RoPE: qkv [B*T][2304] -> qh [B][H][T][128] (q pre-scaled), kh [B][T][128] ----------
#define QSC 0.031879358f
__global__ __launch_bounds__(256) void rope_kernel(const short* __restrict__ qkv,
                                                   const float* __restrict__ cosb,
                                                   const float* __restrict__ sinb,
                                                   short* __restrict__ qh,
                                                   short* __restrict__ kh) {
  const int bt = blockIdx.x;
  const int b = bt >> 11, t = bt & 2047;
  const int tid = threadIdx.x;
  {
    int h = tid >> 4, d0 = (tid & 15) * 8;
    const short* base = qkv + (size_t)bt * 2304 + h * 128;
    bf16x8 qa = *(const bf16x8*)(base + d0);
    int dp = d0 < 64 ? d0 + 64 : d0 - 64;
    bf16x8 qp = *(const bf16x8*)(base + dp);
    const float* cp = cosb + (size_t)bt * 128 + d0;
    const float* sp = sinb + (size_t)bt * 128 + d0;
    float sgn = d0 < 64 ? -1.f : 1.f;
    bf16x8 r;
#pragma unroll
    for (int e = 0; e < 8; ++e)
      r[e] = f2b((b2f(qa[e]) * cp[e] + sgn * b2f(qp[e]) * sp[e]) * QSC);
    *(bf16x8*)(qh + (((size_t)(b * 16 + h) * 2048 + t) * 128 + d0)) = r;
  }
  if (tid < 16) {
    int d0 = tid * 8;
    const short* base = qkv + (size_t)bt * 2304 + 2048;
    bf16x8 ka = *(const bf16x8*)(base + d0);
    int dp = d0 < 64 ? d0 + 64 : d0 - 64;
    bf16x8 kp = *(const bf16x8*)(base + dp);
    const float* cp = cosb + (size_t)bt * 128 + d0;
    const float* sp = sinb + (size_t)bt * 128 + d0;
    float sgn = d0 < 64 ? -1.f : 1.f;
    bf16x8 r;
#pragma unroll
    for (int e = 0; e < 8; ++e)
      r[e] = f2b(b2f(ka[e]) * cp[e] + sgn * b2f(kp[e]) * sp[e]);
    *(bf16x8*)(kh + ((size_t)bt * 128 + d0)) = r;
  }
}

// ---------- V transpose: qkv v-cols -> vt [B][128][T] ----------
__global__ __launch_bounds__(256) void vtrans_kernel(const short* __restrict__ qkv,
                                                     short* __restrict__ vt) {
  __shared__ short tile[64][33];
  const int tid = threadIdx.x;
  const int t0 = blockIdx.x * 64, d0 = blockIdx.y * 32, b = blockIdx.z;
  {
    int dl = tid & 31, tl0 = tid >> 5;
#pragma unroll
    for (int r = 0; r < 8; ++r) {
      int tl = tl0 + r * 8;
      tile[tl][dl] = qkv[(size_t)(b * 2048 + t0 + tl) * 2304 + 2176 + d0 + dl];
    }
  }
  __syncthreads();
  {
    int dl = tid >> 3, s0 = (tid & 7) * 8;
    bf16x8 v;
#pragma unroll
    for (int e = 0; e < 8; ++e) v[e] = tile[s0 + e][dl];
    *(bf16x8*)(vt + (size_t)(b * 128 + d0 + dl) * 2048 + t0 + s0) = v;
  }
}

// ---------- causal MQA flash attention v19: 16-wave kv-quarter split (4 waves/SIMD) ----------
// v16 (KVBLK=128: 105->80) and v18 (8 waves: 80->66) validated the model: cost = latency
// exposure around sync events, cut by more waves/SIMD at constant work + events.
// v19: same 128KB LDS, same 17 steps, 1024 threads = 16 waves -> 4 waves/SIMD.
// Wave (wq=wid&3, wp=wid>>2) computes q-strip wq x kv-QUARTER wp (per step: 8 QK +
// 8 PV MFMA, 1 sub-block). VGPR < 128 (one S, pf[2]) so all 16 waves co-reside.
// Static-max softmax partials combine in a 2-round tree per phase:
//   R1: wp=2 -> Ks scratch, wp=3 -> Vts scratch; wp=0 += R(Ks), wp=1 += R(Vts)
//   R2: wp=1 -> Ks scratch, wp>=1 lacc -> Vts; wp=0 += R(Ks), sums laccs, stores.
__global__ __launch_bounds__(1024) void attn_kernel(const short* __restrict__ qh,
                                                    const short* __restrict__ kh,
                                                    const short* __restrict__ vt,
                                                    short* __restrict__ ao) {
  __shared__ short Ks[2][128 * 128];   // [kv][d] 256B rows, 32KB/buf (also combine scratch)
  __shared__ short Vts[2][128 * 128];  // [d][kv] 256B rows, 32KB/buf (also combine scratch)
  const int tid = threadIdx.x, lane = tid & 63, wid = tid >> 6;  // wid 0..15
  const int c = lane & 31, hi = lane >> 5;
  const int wq = wid & 3;   // q-strip (32 rows of the 128-q supertile)
  const int wp = wid >> 2;  // kv-quarter (32 rows of the 128-kv tile)
  const int pi = blockIdx.x;  // 0..7
  const int h = blockIdx.y, b = blockIdx.z;

  // staging: linear LDS dest o = tid*16 + r*16384 (1024 thr x 2 rounds x 16B = 32KB);
  // source pre-unswizzled with the involution u = o ^ (((o>>8)&15)<<4).
  int kof[2], vof[2];
#pragma unroll
  for (int r = 0; r < 2; ++r) {
    int o = tid * 16 + r * 16384;
    int u = o ^ (((o >> 8) & 15) << 4);
    kof[r] = u;                            // K: row(kv)*256 + col
    vof[r] = (u >> 8) * 4096 + (u & 255);  // Vt: d = u>>8 (global row 4096B), kv*2
  }
  const char* kgb = (const char*)kh + (size_t)b * 524288;
  const char* vgb = (const char*)vt + (size_t)b * 524288;
  const int ldsu = wid * 1024;  // wave-uniform dest part (lane*16 added by HW)

  auto STAGE = [&](int bufp, int st) {  // st in 128-kv tiles
    char* kd = (char*)Ks[bufp] + ldsu;
    char* vd = (char*)Vts[bufp] + ldsu;
    const char* kgs = kgb + st * 32768;  // s0*256 bytes
    const char* vgs = vgb + st * 256;    // s0*2 bytes
#pragma unroll
    for (int r = 0; r < 2; ++r) load_lds16(kgs + kof[r], kd + r * 16384);
#pragma unroll
    for (int r = 0; r < 2; ++r) load_lds16(vgs + vof[r], vd + r * 16384);
  };

#pragma unroll 1
  for (int ph = 0; ph < 2; ++ph) {
    const int qt = ph ? (15 - pi) : pi;   // 128-q supertile index
    const int q0 = qt * 128 + wq * 32;    // this wave's 32-q strip
    const int qv = q0 + c;
    const int n = qt + 1;                 // 128-kv tiles needed

    if (ph) __syncthreads();  // combine-scratch reads of ph=0 done before re-staging

    bf16x8 qf[8];
    const short* qbase = qh + ((size_t)(b * 16 + h) * 2048 + qv) * 128;
#pragma unroll
    for (int ki = 0; ki < 8; ++ki) qf[ki] = *(const bf16x8*)(qbase + ki * 16 + hi * 8);

    f32x16 OT[4];
#pragma unroll
    for (int d = 0; d < 4; ++d) OT[d] = zero16();
    float lacc = 0.f;

    asm volatile("s_waitcnt vmcnt(0)" ::: "memory");  // drain qf loads
    STAGE(0, 0);
    int p = 0;
#pragma unroll 1
    for (int st = 0; st < n; ++st) {
      asm volatile("s_waitcnt vmcnt(0)" ::: "memory");
      barrier_raw();
      if (st + 1 < n) STAGE(p ^ 1, st + 1);

      const char* Ksb = (const char*)Ks[p];
      const char* Vtb = (const char*)Vts[p];
      const bool diag = (st == qt);  // sub-block wp valid iff wp <= wq

      if (!(diag && wp > wq)) {  // wave-uniform skip of fully-masked sub-blocks
        // ---- S = K[32wp..32wp+31] Q^T ----
        f32x16 S = zero16();
        __builtin_amdgcn_s_setprio(1);
#pragma unroll
        for (int ki = 0; ki < 8; ++ki) {
          int a0 = (32 * wp + c) * 256 + ((ki * 32 + hi * 16) ^ ((c & 15) << 4));
          bf16x8 kf = *(const bf16x8*)(Ksb + a0);
          S = mfma32(kf, qf[ki], S);
        }
        __builtin_amdgcn_s_setprio(0);

        // ---- causal mask (only the wp == wq sub-block of the diagonal tile) ----
        if (diag && wp == wq) {
#pragma unroll
          for (int r = 0; r < 16; ++r) {
            int kvl = (r & 3) + 8 * (r >> 2) + hi * 4;
            S[r] = (kvl > c) ? -1e30f : S[r];
          }
        }

        // ---- P = exp2(S) (static max = 0), per-lane partial row-sum ----
        float ps0 = 0.f, ps1 = 0.f, ps2 = 0.f, ps3 = 0.f;
#pragma unroll
        for (int r = 0; r < 16; r += 4) {
          S[r] = exp2r(S[r]);          ps0 += S[r];
          S[r + 1] = exp2r(S[r + 1]);  ps1 += S[r + 1];
          S[r + 2] = exp2r(S[r + 2]);  ps2 += S[r + 2];
          S[r + 3] = exp2r(S[r + 3]);  ps3 += S[r + 3];
        }
        lacc += (ps0 + ps1) + (ps2 + ps3);

        // ---- pack P -> bf16 + cross-half redistribution (all-VALU) ----
        unsigned D[8];
#pragma unroll
        for (int i = 0; i < 8; ++i) D[i] = pack2(S[2 * i], S[2 * i + 1]);
        unsigned a0 = D[0], a1 = D[1], a2 = D[2], a3 = D[3];
        swap32(a0, a2);
        swap32(a1, a3);
        u32x4 w0;
        w0[0] = a0; w0[1] = a1; w0[2] = a2; w0[3] = a3;
        bf16x8 pf0 = __builtin_bit_cast(bf16x8, w0);
        unsigned b0 = D[4], b1 = D[5], b2 = D[6], b3 = D[7];
        swap32(b0, b2);
        swap32(b1, b3);
        u32x4 w1;
        w1[0] = b0; w1[1] = b1; w1[2] = b2; w1[3] = b3;
        bf16x8 pf1 = __builtin_bit_cast(bf16x8, w1);

        // ---- O^T += V^T P (this wave's kv-quarter) ----
        __builtin_amdgcn_s_setprio(1);
#pragma unroll
        for (int dblk = 0; dblk < 4; ++dblk) {
          int rbase = (dblk * 32 + c) * 256;
          int sw = (c & 15) << 4;
          int av0 = rbase + ((wp * 64 + hi * 16) ^ sw);
          bf16x8 vf0 = *(const bf16x8*)(Vtb + av0);
          OT[dblk] = mfma32(vf0, pf0, OT[dblk]);
          int av1 = rbase + ((wp * 64 + 32 + hi * 16) ^ sw);
          bf16x8 vf1 = *(const bf16x8*)(Vtb + av1);
          OT[dblk] = mfma32(vf1, pf1, OT[dblk]);
        }
        __builtin_amdgcn_s_setprio(0);
      }

      p ^= 1;
    }

    // ---- cross-quarter combine (2-round tree) ----
    __syncthreads();  // all waves done reading K/V bufs; no staging pending
    char* RA = (char*)Ks + wq * 16384;         // 16KB per strip; 4 strips = 64KB (Ks)
    char* RB = (char*)Vts + wq * 16384;        // 16KB per strip; 4 strips = 64KB (Vts)
    float* LB = (float*)Vts;                   // lacc scratch (768 floats), round 2

    auto PUB = [&](char* R) {
#pragma unroll
      for (int dblk = 0; dblk < 4; ++dblk)
#pragma unroll
        for (int rq = 0; rq < 4; ++rq) {
          int off = (lane * 256 + (dblk * 4 + rq) * 16) ^ ((lane & 15) << 4);
          f32x4 piece;
          piece[0] = OT[dblk][4 * rq];
          piece[1] = OT[dblk][4 * rq + 1];
          piece[2] = OT[dblk][4 * rq + 2];
          piece[3] = OT[dblk][4 * rq + 3];
          *(f32x4*)(R + off) = piece;
        }
    };
    auto RED = [&](const char* R) {
#pragma unroll
      for (int dblk = 0; dblk < 4; ++dblk)
#pragma unroll
        for (int rq = 0; rq < 4; ++rq) {
          int off = (lane * 256 + (dblk * 4 + rq) * 16) ^ ((lane & 15) << 4);
          f32x4 piece = *(const f32x4*)(R + off);
          OT[dblk][4 * rq] += piece[0];
          OT[dblk][4 * rq + 1] += piece[1];
          OT[dblk][4 * rq + 2] += piece[2];
          OT[dblk][4 * rq + 3] += piece[3];
        }
    };

    if (wp == 2) PUB(RA);
    if (wp == 3) PUB(RB);
    __syncthreads();
    if (wp == 0) RED(RA);   // OT0 += OT2
    if (wp == 1) RED(RB);   // OT1 += OT3
    __syncthreads();
    if (wp == 1) PUB(RA);   // publish (1+3)
    if (wp >= 1) LB[wq * 192 + (wp - 1) * 64 + lane] = lacc;
    __syncthreads();
    if (wp == 0) {
      RED(RA);              // OT = 0+1+2+3
      float lsum = lacc + LB[wq * 192 + lane] + LB[wq * 192 + 64 + lane] +
                   LB[wq * 192 + 128 + lane];
      float inv = 1.f / xhalfsum(lsum);

      // epilogue: O^T / lsum -> ao[b][q][h][d], paired-d dword stores
      short* aob = ao + ((size_t)(b * 2048 + qv) * 2048 + h * 128);
#pragma unroll
      for (int dblk = 0; dblk < 4; ++dblk) {
#pragma unroll
        for (int rp = 0; rp < 8; ++rp) {
          int r = rp * 2;
          int dd = dblk * 32 + (r & 3) + 8 * (r >> 2) + hi * 4;
          unsigned w = pack2(OT[dblk][r] * inv, OT[dblk][r + 1] * inv);
          *(unsigned*)(aob + dd) = w;
        }
      }
    }
  }
}

// ---------- launch ----------
extern "C" void kernel_launch(void* const* d_in, const int* in_sizes, int n_in,
                              void* d_out, int out_size, void* d_ws, size_t ws_size,
                              hipStream_t stream) {
  const float* x = (const float*)d_in[0];
  const float* cosb = (const float*)d_in[1];
  const float* sinb = (const float*)d_in[2];
  const float* Wq = (const float*)d_in[3];
  const float* Wk = (const float*)d_in[4];
  const float* Wv = (const float*)d_in[5];
  const float* Wo = (const float*)d_in[6];

  char* ws = (char*)d_ws;
  short* xb = (short*)(ws);                    // 16.78 MB  (aliased as ao later)
  short* wcat = (short*)(ws + 16777216);       // 9.44 MB
  short* wob = (short*)(ws + 26214400);        // 8.39 MB
  short* qkv = (short*)(ws + 34603008);        // 18.87 MB
  short* qh = (short*)(ws + 53477376);         // 16.78 MB
  short* kh = (short*)(ws + 70254592);         // 1.05 MB
  short* vt = (short*)(ws + 71303168);         // 1.05 MB
  short* ao = xb;                              // xb dead after gemm1

  cvt_all_kernel<<<8448, 256, 0, stream>>>(x, Wq, Wk, Wv, Wo, xb, wcat, wob);

  gemm_nt<1><<<576, 256, 0, stream>>>(xb, wcat, qkv, 4096, 2304, 2048);
  rope_kernel<<<4096, 256, 0, stream>>>(qkv, cosb, sinb, qh, kh);
  vtrans_kernel<<<dim3(32, 4, 2), 256, 0, stream>>>(qkv, vt);
  attn_kernel<<<dim3(8, 16, 2), 1024, 0, stream>>>(qh, kh, vt, ao);
  gemm_nt<0><<<512, 256, 0, stream>>>(ao, wob, d_out, 4096, 2048, 2048);
}

// Round 10
// 207.149 us; speedup vs baseline: 1.0097x; 1.0097x over previous
//
#include <hip/hip_runtime.h>
#include <hip/hip_bf16.h>

// ---------- types ----------
typedef __attribute__((ext_vector_type(8))) short bf16x8;
typedef __attribute__((ext_vector_type(4))) float f32x4;
typedef __attribute__((ext_vector_type(16))) float f32x16;
typedef __attribute__((ext_vector_type(4))) unsigned u32x4;

#define DEVINL static __device__ __forceinline__
#define GLOBAL_AS __attribute__((address_space(1)))
#define LDS_AS __attribute__((address_space(3)))

DEVINL short f2b(float f) {
  __hip_bfloat16 h = __float2bfloat16(f);
  return __builtin_bit_cast(short, h);
}
DEVINL float b2f(short s) {
  return __bfloat162float(__builtin_bit_cast(__hip_bfloat16, s));
}
// packed f32->bf16 (RNE) : low = a, high = b. One VALU inst.
DEVINL unsigned pack2(float a, float b) {
  unsigned r;
  asm("v_cvt_pk_bf16_f32 %0, %1, %2" : "=v"(r) : "v"(a), "v"(b));
  return r;
}
// dst.hi(lanes 32-63) <-> src.lo(lanes 0-31) exchange, pure VALU
DEVINL void swap32(unsigned& x, unsigned& y) {
  asm("v_permlane32_swap_b32 %0, %1" : "+v"(x), "+v"(y));
}
// v + (v from lane^32); opaque mov keeps asm operands in distinct registers
DEVINL float xhalfsum(float v) {
  float t;
  asm("v_mov_b32 %0, %1" : "=v"(t) : "v"(v));
  asm("v_permlane32_swap_b32 %0, %1" : "+v"(v), "+v"(t));
  return v + t;
}
// raw hardware exp2 (1 transcendental inst; handles -1e30 -> 0 underflow)
DEVINL float exp2r(float x) {
  float r;
  asm("v_exp_f32 %0, %1" : "=v"(r) : "v"(x));
  return r;
}
DEVINL void load_lds16(const void* g, void* l) {
  __builtin_amdgcn_global_load_lds((const GLOBAL_AS void*)g, (LDS_AS void*)l, 16, 0, 0);
}
DEVINL void barrier_raw() {
  __builtin_amdgcn_sched_barrier(0);
  __builtin_amdgcn_s_barrier();
  __builtin_amdgcn_sched_barrier(0);
}
DEVINL f32x16 mfma32(bf16x8 a, bf16x8 b, f32x16 c) {
  return __builtin_amdgcn_mfma_f32_32x32x16_bf16(a, b, c, 0, 0, 0);
}
DEVINL f32x16 zero16() {
  f32x16 z;
#pragma unroll
  for (int i = 0; i < 16; ++i) z[i] = 0.f;
  return z;
}

// ---------- fused fp32 -> bf16 conversion (x, Wq, Wk, Wv, Wo in one launch) ----------
__global__ __launch_bounds__(256) void cvt_all_kernel(const float* __restrict__ x,
                                                      const float* __restrict__ wq,
                                                      const float* __restrict__ wk,
                                                      const float* __restrict__ wv,
                                                      const float* __restrict__ wo,
                                                      short* __restrict__ xb,
                                                      short* __restrict__ wcat,
                                                      short* __restrict__ wob) {
  int i = blockIdx.x * blockDim.x + threadIdx.x;
  if (i >= 2162688) return;
  const float* src;
  short* dst;
  if (i < 1048576) {
    src = x + (size_t)i * 8;
    dst = xb + (size_t)i * 8;
  } else if (i < 1572864) {
    int j = i - 1048576;
    src = wq + (size_t)j * 8;
    dst = wcat + (size_t)j * 8;
  } else if (i < 1605632) {
    int j = i - 1572864;
    src = wk + (size_t)j * 8;
    dst = wcat + 4194304 + (size_t)j * 8;
  } else if (i < 1638400) {
    int j = i - 1605632;
    src = wv + (size_t)j * 8;
    dst = wcat + 4456448 + (size_t)j * 8;
  } else {
    int j = i - 1638400;
    src = wo + (size_t)j * 8;
    dst = wob + (size_t)j * 8;
  }
  const float4* p = reinterpret_cast<const float4*>(src);
  float4 a = p[0], b = p[1];
  bf16x8 v;
  v[0] = f2b(a.x); v[1] = f2b(a.y); v[2] = f2b(a.z); v[3] = f2b(a.w);
  v[4] = f2b(b.x); v[5] = f2b(b.y); v[6] = f2b(b.z); v[7] = f2b(b.w);
  *reinterpret_cast<bf16x8*>(dst) = v;
}

// ---------- NT GEMM: C[m][n] = sum_k A[m][k]*B[n][k], A [M][K], B [N][K] bf16 ----------
template <int BF16OUT>
__global__ __launch_bounds__(256) void gemm_nt(const short* __restrict__ A,
                                               const short* __restrict__ B,
                                               void* __restrict__ Cv, int M, int N, int K) {
  __shared__ short As[128 * 64];
  __shared__ short Bs[128 * 64];
  const int tid = threadIdx.x;
  const int lane = tid & 63;
  const int wid = tid >> 6;
  const int lr = lane & 15, lg = lane >> 4;
  const int nwg = gridDim.x, cpx = nwg >> 3;
  const int lid = blockIdx.x;
  const int swz = (lid & 7) * cpx + (lid >> 3);
  const int nbn = N >> 7;
  const int bn = swz % nbn, bm = swz / nbn;
  const int wr = wid >> 1, wc = wid & 1;

  f32x4 acc[4][4];
#pragma unroll
  for (int i = 0; i < 4; ++i)
#pragma unroll
    for (int j = 0; j < 4; ++j) acc[i][j] = f32x4{0.f, 0.f, 0.f, 0.f};

  const short* Ag[4];
  const short* Bg[4];
#pragma unroll
  for (int j = 0; j < 4; ++j) {
    int o = j * 4096 + tid * 16;
    int row = o >> 7;
    int src = o ^ ((row & 7) << 4);
    int col = (src & 127) >> 1;
    Ag[j] = A + (size_t)(bm * 128 + row) * K + col;
    Bg[j] = B + (size_t)(bn * 128 + row) * K + col;
  }
  char* Asb = (char*)As;
  char* Bsb = (char*)Bs;
  const int lds_w = wid * 1024;

  for (int kt = 0; kt < K; kt += 64) {
    __syncthreads();
#pragma unroll
    for (int j = 0; j < 4; ++j) load_lds16(Ag[j] + kt, Asb + j * 4096 + lds_w);
#pragma unroll
    for (int j = 0; j < 4; ++j) load_lds16(Bg[j] + kt, Bsb + j * 4096 + lds_w);
    __syncthreads();

#pragma unroll
    for (int kc = 0; kc < 2; ++kc) {
      bf16x8 af[4], bfr[4];
#pragma unroll
      for (int mf = 0; mf < 4; ++mf) {
        int row = wr * 64 + mf * 16 + lr;
        int a_ = (row * 128 + kc * 64 + lg * 16) ^ ((row & 7) << 4);
        af[mf] = *(const bf16x8*)(Asb + a_);
      }
#pragma unroll
      for (int nf = 0; nf < 4; ++nf) {
        int row = wc * 64 + nf * 16 + lr;
        int a_ = (row * 128 + kc * 64 + lg * 16) ^ ((row & 7) << 4);
        bfr[nf] = *(const bf16x8*)(Bsb + a_);
      }
#pragma unroll
      for (int mf = 0; mf < 4; ++mf)
#pragma unroll
        for (int nf = 0; nf < 4; ++nf)
          acc[mf][nf] =
              __builtin_amdgcn_mfma_f32_16x16x32_bf16(af[mf], bfr[nf], acc[mf][nf], 0, 0, 0);
    }
  }

#pragma unroll
  for (int mf = 0; mf < 4; ++mf)
#pragma unroll
    for (int nf = 0; nf < 4; ++nf)
#pragma unroll
      for (int j = 0; j < 4; ++j) {
        int row = bm * 128 + wr * 64 + mf * 16 + lg * 4 + j;
        int col = bn * 128 + wc * 64 + nf * 16 + lr;
        if constexpr (BF16OUT)
          ((short*)Cv)[(size_t)row * N + col] = f2b(acc[mf][nf][j]);
        else
          ((float*)Cv)[(size_t)row * N + col] = acc[mf][nf][j];
      }
}

// ---------- RoPE: qkv [B*T][2304] -> qh [B][H][T][128] (q pre-scaled), kh [B][T][128] ----------
#define QSC 0.031879358f
__global__ __launch_bounds__(256) void rope_kernel(const short* __restrict__ qkv,
                                                   const float* __restrict__ cosb,
                                                   const float* __restrict__ sinb,
                                                   short* __restrict__ qh,
                                                   short* __restrict__ kh) {
  const int bt = blockIdx.x;
  const int b = bt >> 11, t = bt & 2047;
  const int tid = threadIdx.x;
  {
    int h = tid >> 4, d0 = (tid & 15) * 8;
    const short* base = qkv + (size_t)bt * 2304 + h * 128;
    bf16x8 qa = *(const bf16x8*)(base + d0);
    int dp = d0 < 64 ? d0 + 64 : d0 - 64;
    bf16x8 qp = *(const bf16x8*)(base + dp);
    const float* cp = cosb + (size_t)bt * 128 + d0;
    const float* sp = sinb + (size_t)bt * 128 + d0;
    float sgn = d0 < 64 ? -1.f : 1.f;
    bf16x8 r;
#pragma unroll
    for (int e = 0; e < 8; ++e)
      r[e] = f2b((b2f(qa[e]) * cp[e] + sgn * b2f(qp[e]) * sp[e]) * QSC);
    *(bf16x8*)(qh + (((size_t)(b * 16 + h) * 2048 + t) * 128 + d0)) = r;
  }
  if (tid < 16) {
    int d0 = tid * 8;
    const short* base = qkv + (size_t)bt * 2304 + 2048;
    bf16x8 ka = *(const bf16x8*)(base + d0);
    int dp = d0 < 64 ? d0 + 64 : d0 - 64;
    bf16x8 kp = *(const bf16x8*)(base + dp);
    const float* cp = cosb + (size_t)bt * 128 + d0;
    const float* sp = sinb + (size_t)bt * 128 + d0;
    float sgn = d0 < 64 ? -1.f : 1.f;
    bf16x8 r;
#pragma unroll
    for (int e = 0; e < 8; ++e)
      r[e] = f2b(b2f(ka[e]) * cp[e] + sgn * b2f(kp[e]) * sp[e]);
    *(bf16x8*)(kh + ((size_t)bt * 128 + d0)) = r;
  }
}

// ---------- V transpose: qkv v-cols -> vt [B][128][T] ----------
__global__ __launch_bounds__(256) void vtrans_kernel(const short* __restrict__ qkv,
                                                     short* __restrict__ vt) {
  __shared__ short tile[64][33];
  const int tid = threadIdx.x;
  const int t0 = blockIdx.x * 64, d0 = blockIdx.y * 32, b = blockIdx.z;
  {
    int dl = tid & 31, tl0 = tid >> 5;
#pragma unroll
    for (int r = 0; r < 8; ++r) {
      int tl = tl0 + r * 8;
      tile[tl][dl] = qkv[(size_t)(b * 2048 + t0 + tl) * 2304 + 2176 + d0 + dl];
    }
  }
  __syncthreads();
  {
    int dl = tid >> 3, s0 = (tid & 7) * 8;
    bf16x8 v;
#pragma unroll
    for (int e = 0; e < 8; ++e) v[e] = tile[s0 + e][dl];
    *(bf16x8*)(vt + (size_t)(b * 128 + d0 + dl) * 2048 + t0 + s0) = v;
  }
}

// ---------- causal MQA flash attention v20: v19 + correct VGPR budget ----------
// v19 post-mortem: the 16-wave kv-quarter split was sound (occupancy hit 41%) but a
// bare __launch_bounds__(1024) let the compiler cap VGPR at 64 (targeting an occupancy
// the 128KB LDS can't reach anyway) -> ~116-reg live set spilled to scratch ->
// 62MB FETCH + 70MB WRITE of spill traffic = the whole regression.
// Fix: __launch_bounds__(1024, 4) — 2nd arg = min waves per EU; 16-wave block at
// 1 blk/CU = 4 waves/SIMD -> VGPR cap 512/4 = 128 >= live set. No spill.
// Everything else identical to v19: 128KB LDS, 17 steps, wave (wq=wid&3, wp=wid>>2)
// computes q-strip wq x kv-quarter wp (8 QK + 8 PV MFMA/step), static-max softmax,
// additive kv-partials combined in a 2-round LDS tree per phase.
__global__ __launch_bounds__(1024, 4) void attn_kernel(const short* __restrict__ qh,
                                                       const short* __restrict__ kh,
                                                       const short* __restrict__ vt,
                                                       short* __restrict__ ao) {
  __shared__ short Ks[2][128 * 128];   // [kv][d] 256B rows, 32KB/buf (also combine scratch)
  __shared__ short Vts[2][128 * 128];  // [d][kv] 256B rows, 32KB/buf (also combine scratch)
  const int tid = threadIdx.x, lane = tid & 63, wid = tid >> 6;  // wid 0..15
  const int c = lane & 31, hi = lane >> 5;
  const int wq = wid & 3;   // q-strip (32 rows of the 128-q supertile)
  const int wp = wid >> 2;  // kv-quarter (32 rows of the 128-kv tile)
  const int pi = blockIdx.x;  // 0..7
  const int h = blockIdx.y, b = blockIdx.z;

  // staging: linear LDS dest o = tid*16 + r*16384 (1024 thr x 2 rounds x 16B = 32KB);
  // source pre-unswizzled with the involution u = o ^ (((o>>8)&15)<<4).
  int kof[2], vof[2];
#pragma unroll
  for (int r = 0; r < 2; ++r) {
    int o = tid * 16 + r * 16384;
    int u = o ^ (((o >> 8) & 15) << 4);
    kof[r] = u;                            // K: row(kv)*256 + col
    vof[r] = (u >> 8) * 4096 + (u & 255);  // Vt: d = u>>8 (global row 4096B), kv*2
  }
  const char* kgb = (const char*)kh + (size_t)b * 524288;
  const char* vgb = (const char*)vt + (size_t)b * 524288;
  const int ldsu = wid * 1024;  // wave-uniform dest part (lane*16 added by HW)

  auto STAGE = [&](int bufp, int st) {  // st in 128-kv tiles
    char* kd = (char*)Ks[bufp] + ldsu;
    char* vd = (char*)Vts[bufp] + ldsu;
    const char* kgs = kgb + st * 32768;  // s0*256 bytes
    const char* vgs = vgb + st * 256;    // s0*2 bytes
#pragma unroll
    for (int r = 0; r < 2; ++r) load_lds16(kgs + kof[r], kd + r * 16384);
#pragma unroll
    for (int r = 0; r < 2; ++r) load_lds16(vgs + vof[r], vd + r * 16384);
  };

#pragma unroll 1
  for (int ph = 0; ph < 2; ++ph) {
    const int qt = ph ? (15 - pi) : pi;   // 128-q supertile index
    const int q0 = qt * 128 + wq * 32;    // this wave's 32-q strip
    const int qv = q0 + c;
    const int n = qt + 1;                 // 128-kv tiles needed

    if (ph) __syncthreads();  // combine-scratch reads of ph=0 done before re-staging

    bf16x8 qf[8];
    const short* qbase = qh + ((size_t)(b * 16 + h) * 2048 + qv) * 128;
#pragma unroll
    for (int ki = 0; ki < 8; ++ki) qf[ki] = *(const bf16x8*)(qbase + ki * 16 + hi * 8);

    f32x16 OT[4];
#pragma unroll
    for (int d = 0; d < 4; ++d) OT[d] = zero16();
    float lacc = 0.f;

    asm volatile("s_waitcnt vmcnt(0)" ::: "memory");  // drain qf loads
    STAGE(0, 0);
    int p = 0;
#pragma unroll 1
    for (int st = 0; st < n; ++st) {
      asm volatile("s_waitcnt vmcnt(0)" ::: "memory");
      barrier_raw();
      if (st + 1 < n) STAGE(p ^ 1, st + 1);

      const char* Ksb = (const char*)Ks[p];
      const char* Vtb = (const char*)Vts[p];
      const bool diag = (st == qt);  // sub-block wp valid iff wp <= wq

      if (!(diag && wp > wq)) {  // wave-uniform skip of fully-masked sub-blocks
        // ---- S = K[32wp..32wp+31] Q^T ----
        f32x16 S = zero16();
        __builtin_amdgcn_s_setprio(1);
#pragma unroll
        for (int ki = 0; ki < 8; ++ki) {
          int a0 = (32 * wp + c) * 256 + ((ki * 32 + hi * 16) ^ ((c & 15) << 4));
          bf16x8 kf = *(const bf16x8*)(Ksb + a0);
          S = mfma32(kf, qf[ki], S);
        }
        __builtin_amdgcn_s_setprio(0);

        // ---- causal mask (only the wp == wq sub-block of the diagonal tile) ----
        if (diag && wp == wq) {
#pragma unroll
          for (int r = 0; r < 16; ++r) {
            int kvl = (r & 3) + 8 * (r >> 2) + hi * 4;
            S[r] = (kvl > c) ? -1e30f : S[r];
          }
        }

        // ---- P = exp2(S) (static max = 0), per-lane partial row-sum ----
        float ps0 = 0.f, ps1 = 0.f, ps2 = 0.f, ps3 = 0.f;
#pragma unroll
        for (int r = 0; r < 16; r += 4) {
          S[r] = exp2r(S[r]);          ps0 += S[r];
          S[r + 1] = exp2r(S[r + 1]);  ps1 += S[r + 1];
          S[r + 2] = exp2r(S[r + 2]);  ps2 += S[r + 2];
          S[r + 3] = exp2r(S[r + 3]);  ps3 += S[r + 3];
        }
        lacc += (ps0 + ps1) + (ps2 + ps3);

        // ---- pack P -> bf16 + cross-half redistribution (all-VALU) ----
        unsigned D[8];
#pragma unroll
        for (int i = 0; i < 8; ++i) D[i] = pack2(S[2 * i], S[2 * i + 1]);
        unsigned a0 = D[0], a1 = D[1], a2 = D[2], a3 = D[3];
        swap32(a0, a2);
        swap32(a1, a3);
        u32x4 w0;
        w0[0] = a0; w0[1] = a1; w0[2] = a2; w0[3] = a3;
        bf16x8 pf0 = __builtin_bit_cast(bf16x8, w0);
        unsigned b0 = D[4], b1 = D[5], b2 = D[6], b3 = D[7];
        swap32(b0, b2);
        swap32(b1, b3);
        u32x4 w1;
        w1[0] = b0; w1[1] = b1; w1[2] = b2; w1[3] = b3;
        bf16x8 pf1 = __builtin_bit_cast(bf16x8, w1);

        // ---- O^T += V^T P (this wave's kv-quarter) ----
        __builtin_amdgcn_s_setprio(1);
#pragma unroll
        for (int dblk = 0; dblk < 4; ++dblk) {
          int rbase = (dblk * 32 + c) * 256;
          int sw = (c & 15) << 4;
          int av0 = rbase + ((wp * 64 + hi * 16) ^ sw);
          bf16x8 vf0 = *(const bf16x8*)(Vtb + av0);
          OT[dblk] = mfma32(vf0, pf0, OT[dblk]);
          int av1 = rbase + ((wp * 64 + 32 + hi * 16) ^ sw);
          bf16x8 vf1 = *(const bf16x8*)(Vtb + av1);
          OT[dblk] = mfma32(vf1, pf1, OT[dblk]);
        }
        __builtin_amdgcn_s_setprio(0);
      }

      p ^= 1;
    }

    // ---- cross-quarter combine (2-round tree) ----
    __syncthreads();  // all waves done reading K/V bufs; no staging pending
    char* RA = (char*)Ks + wq * 16384;         // 16KB per strip; 4 strips = 64KB (Ks)
    char* RB = (char*)Vts + wq * 16384;        // 16KB per strip; 4 strips = 64KB (Vts)
    float* LB = (float*)Vts;                   // lacc scratch (768 floats), round 2

    auto PUB = [&](char* R) {
#pragma unroll
      for (int dblk = 0; dblk < 4; ++dblk)
#pragma unroll
        for (int rq = 0; rq < 4; ++rq) {
          int off = (lane * 256 + (dblk * 4 + rq) * 16) ^ ((lane & 15) << 4);
          f32x4 piece;
          piece[0] = OT[dblk][4 * rq];
          piece[1] = OT[dblk][4 * rq + 1];
          piece[2] = OT[dblk][4 * rq + 2];
          piece[3] = OT[dblk][4 * rq + 3];
          *(f32x4*)(R + off) = piece;
        }
    };
    auto RED = [&](const char* R) {
#pragma unroll
      for (int dblk = 0; dblk < 4; ++dblk)
#pragma unroll
        for (int rq = 0; rq < 4; ++rq) {
          int off = (lane * 256 + (dblk * 4 + rq) * 16) ^ ((lane & 15) << 4);
          f32x4 piece = *(const f32x4*)(R + off);
          OT[dblk][4 * rq] += piece[0];
          OT[dblk][4 * rq + 1] += piece[1];
          OT[dblk][4 * rq + 2] += piece[2];
          OT[dblk][4 * rq + 3] += piece[3];
        }
    };

    if (wp == 2) PUB(RA);
    if (wp == 3) PUB(RB);
    __syncthreads();
    if (wp == 0) RED(RA);   // OT0 += OT2
    if (wp == 1) RED(RB);   // OT1 += OT3
    __syncthreads();
    if (wp == 1) PUB(RA);   // publish (1+3)
    if (wp >= 1) LB[wq * 192 + (wp - 1) * 64 + lane] = lacc;
    __syncthreads();
    if (wp == 0) {
      RED(RA);              // OT = 0+1+2+3
      float lsum = lacc + LB[wq * 192 + lane] + LB[wq * 192 + 64 + lane] +
                   LB[wq * 192 + 128 + lane];
      float inv = 1.f / xhalfsum(lsum);

      // epilogue: O^T / lsum -> ao[b][q][h][d], paired-d dword stores
      short* aob = ao + ((size_t)(b * 2048 + qv) * 2048 + h * 128);
#pragma unroll
      for (int dblk = 0; dblk < 4; ++dblk) {
#pragma unroll
        for (int rp = 0; rp < 8; ++rp) {
          int r = rp * 2;
          int dd = dblk * 32 + (r & 3) + 8 * (r >> 2) + hi * 4;
          unsigned w = pack2(OT[dblk][r] * inv, OT[dblk][r + 1] * inv);
          *(unsigned*)(aob + dd) = w;
        }
      }
    }
  }
}

// ---------- launch ----------
extern "C" void kernel_launch(void* const* d_in, const int* in_sizes, int n_in,
                              void* d_out, int out_size, void* d_ws, size_t ws_size,
                              hipStream_t stream) {
  const float* x = (const float*)d_in[0];
  const float* cosb = (const float*)d_in[1];
  const float* sinb = (const float*)d_in[2];
  const float* Wq = (const float*)d_in[3];
  const float* Wk = (const float*)d_in[4];
  const float* Wv = (const float*)d_in[5];
  const float* Wo = (const float*)d_in[6];

  char* ws = (char*)d_ws;
  short* xb = (short*)(ws);                    // 16.78 MB  (aliased as ao later)
  short* wcat = (short*)(ws + 16777216);       // 9.44 MB
  short* wob = (short*)(ws + 26214400);        // 8.39 MB
  short* qkv = (short*)(ws + 34603008);        // 18.87 MB
  short* qh = (short*)(ws + 53477376);         // 16.78 MB
  short* kh = (short*)(ws + 70254592);         // 1.05 MB
  short* vt = (short*)(ws + 71303168);         // 1.05 MB
  short* ao = xb;                              // xb dead after gemm1

  cvt_all_kernel<<<8448, 256, 0, stream>>>(x, Wq, Wk, Wv, Wo, xb, wcat, wob);

  gemm_nt<1><<<576, 256, 0, stream>>>(xb, wcat, qkv, 4096, 2304, 2048);
  rope_kernel<<<4096, 256, 0, stream>>>(qkv, cosb, sinb, qh, kh);
  vtrans_kernel<<<dim3(32, 4, 2), 256, 0, stream>>>(qkv, vt);
  attn_kernel<<<dim3(8, 16, 2), 1024, 0, stream>>>(qh, kh, vt, ao);
  gemm_nt<0><<<512, 256, 0, stream>>>(ao, wob, d_out, 4096, 2048, 2048);
}

// Round 11
// 170.672 us; speedup vs baseline: 1.2254x; 1.2137x over previous
//
#include <hip/hip_runtime.h>
#include <hip/hip_bf16.h>

// ---------- types ----------
typedef __attribute__((ext_vector_type(8))) short bf16x8;
typedef __attribute__((ext_vector_type(4))) float f32x4;
typedef __attribute__((ext_vector_type(16))) float f32x16;
typedef __attribute__((ext_vector_type(4))) unsigned u32x4;

#define DEVINL static __device__ __forceinline__
#define GLOBAL_AS __attribute__((address_space(1)))
#define LDS_AS __attribute__((address_space(3)))

DEVINL short f2b(float f) {
  __hip_bfloat16 h = __float2bfloat16(f);
  return __builtin_bit_cast(short, h);
}
DEVINL float b2f(short s) {
  return __bfloat162float(__builtin_bit_cast(__hip_bfloat16, s));
}
// packed f32->bf16 (RNE) : low = a, high = b. One VALU inst.
DEVINL unsigned pack2(float a, float b) {
  unsigned r;
  asm("v_cvt_pk_bf16_f32 %0, %1, %2" : "=v"(r) : "v"(a), "v"(b));
  return r;
}
// dst.hi(lanes 32-63) <-> src.lo(lanes 0-31) exchange, pure VALU
DEVINL void swap32(unsigned& x, unsigned& y) {
  asm("v_permlane32_swap_b32 %0, %1" : "+v"(x), "+v"(y));
}
// v + (v from lane^32); opaque mov keeps asm operands in distinct registers
DEVINL float xhalfsum(float v) {
  float t;
  asm("v_mov_b32 %0, %1" : "=v"(t) : "v"(v));
  asm("v_permlane32_swap_b32 %0, %1" : "+v"(v), "+v"(t));
  return v + t;
}
// raw hardware exp2 (1 transcendental inst; handles -1e30 -> 0 underflow)
DEVINL float exp2r(float x) {
  float r;
  asm("v_exp_f32 %0, %1" : "=v"(r) : "v"(x));
  return r;
}
DEVINL void load_lds16(const void* g, void* l) {
  __builtin_amdgcn_global_load_lds((const GLOBAL_AS void*)g, (LDS_AS void*)l, 16, 0, 0);
}
DEVINL void barrier_raw() {
  __builtin_amdgcn_sched_barrier(0);
  __builtin_amdgcn_s_barrier();
  __builtin_amdgcn_sched_barrier(0);
}
DEVINL f32x16 mfma32(bf16x8 a, bf16x8 b, f32x16 c) {
  return __builtin_amdgcn_mfma_f32_32x32x16_bf16(a, b, c, 0, 0, 0);
}
DEVINL f32x16 zero16() {
  f32x16 z;
#pragma unroll
  for (int i = 0; i < 16; ++i) z[i] = 0.f;
  return z;
}

// ---------- fused fp32 -> bf16 conversion (x, Wq, Wk, Wv, Wo in one launch) ----------
__global__ __launch_bounds__(256) void cvt_all_kernel(const float* __restrict__ x,
                                                      const float* __restrict__ wq,
                                                      const float* __restrict__ wk,
                                                      const float* __restrict__ wv,
                                                      const float* __restrict__ wo,
                                                      short* __restrict__ xb,
                                                      short* __restrict__ wcat,
                                                      short* __restrict__ wob) {
  int i = blockIdx.x * blockDim.x + threadIdx.x;
  if (i >= 2162688) return;
  const float* src;
  short* dst;
  if (i < 1048576) {
    src = x + (size_t)i * 8;
    dst = xb + (size_t)i * 8;
  } else if (i < 1572864) {
    int j = i - 1048576;
    src = wq + (size_t)j * 8;
    dst = wcat + (size_t)j * 8;
  } else if (i < 1605632) {
    int j = i - 1572864;
    src = wk + (size_t)j * 8;
    dst = wcat + 4194304 + (size_t)j * 8;
  } else if (i < 1638400) {
    int j = i - 1605632;
    src = wv + (size_t)j * 8;
    dst = wcat + 4456448 + (size_t)j * 8;
  } else {
    int j = i - 1638400;
    src = wo + (size_t)j * 8;
    dst = wob + (size_t)j * 8;
  }
  const float4* p = reinterpret_cast<const float4*>(src);
  float4 a = p[0], b = p[1];
  bf16x8 v;
  v[0] = f2b(a.x); v[1] = f2b(a.y); v[2] = f2b(a.z); v[3] = f2b(a.w);
  v[4] = f2b(b.x); v[5] = f2b(b.y); v[6] = f2b(b.z); v[7] = f2b(b.w);
  *reinterpret_cast<bf16x8*>(dst) = v;
}

// ---------- NT GEMM: C[m][n] = sum_k A[m][k]*B[n][k], A [M][K], B [N][K] bf16 ----------
template <int BF16OUT>
__global__ __launch_bounds__(256) void gemm_nt(const short* __restrict__ A,
                                               const short* __restrict__ B,
                                               void* __restrict__ Cv, int M, int N, int K) {
  __shared__ short As[128 * 64];
  __shared__ short Bs[128 * 64];
  const int tid = threadIdx.x;
  const int lane = tid & 63;
  const int wid = tid >> 6;
  const int lr = lane & 15, lg = lane >> 4;
  const int nwg = gridDim.x, cpx = nwg >> 3;
  const int lid = blockIdx.x;
  const int swz = (lid & 7) * cpx + (lid >> 3);
  const int nbn = N >> 7;
  const int bn = swz % nbn, bm = swz / nbn;
  const int wr = wid >> 1, wc = wid & 1;

  f32x4 acc[4][4];
#pragma unroll
  for (int i = 0; i < 4; ++i)
#pragma unroll
    for (int j = 0; j < 4; ++j) acc[i][j] = f32x4{0.f, 0.f, 0.f, 0.f};

  const short* Ag[4];
  const short* Bg[4];
#pragma unroll
  for (int j = 0; j < 4; ++j) {
    int o = j * 4096 + tid * 16;
    int row = o >> 7;
    int src = o ^ ((row & 7) << 4);
    int col = (src & 127) >> 1;
    Ag[j] = A + (size_t)(bm * 128 + row) * K + col;
    Bg[j] = B + (size_t)(bn * 128 + row) * K + col;
  }
  char* Asb = (char*)As;
  char* Bsb = (char*)Bs;
  const int lds_w = wid * 1024;

  for (int kt = 0; kt < K; kt += 64) {
    __syncthreads();
#pragma unroll
    for (int j = 0; j < 4; ++j) load_lds16(Ag[j] + kt, Asb + j * 4096 + lds_w);
#pragma unroll
    for (int j = 0; j < 4; ++j) load_lds16(Bg[j] + kt, Bsb + j * 4096 + lds_w);
    __syncthreads();

#pragma unroll
    for (int kc = 0; kc < 2; ++kc) {
      bf16x8 af[4], bfr[4];
#pragma unroll
      for (int mf = 0; mf < 4; ++mf) {
        int row = wr * 64 + mf * 16 + lr;
        int a_ = (row * 128 + kc * 64 + lg * 16) ^ ((row & 7) << 4);
        af[mf] = *(const bf16x8*)(Asb + a_);
      }
#pragma unroll
      for (int nf = 0; nf < 4; ++nf) {
        int row = wc * 64 + nf * 16 + lr;
        int a_ = (row * 128 + kc * 64 + lg * 16) ^ ((row & 7) << 4);
        bfr[nf] = *(const bf16x8*)(Bsb + a_);
      }
#pragma unroll
      for (int mf = 0; mf < 4; ++mf)
#pragma unroll
        for (int nf = 0; nf < 4; ++nf)
          acc[mf][nf] =
              __builtin_amdgcn_mfma_f32_16x16x32_bf16(af[mf], bfr[nf], acc[mf][nf], 0, 0, 0);
    }
  }

#pragma unroll
  for (int mf = 0; mf < 4; ++mf)
#pragma unroll
    for (int nf = 0; nf < 4; ++nf)
#pragma unroll
      for (int j = 0; j < 4; ++j) {
        int row = bm * 128 + wr * 64 + mf * 16 + lg * 4 + j;
        int col = bn * 128 + wc * 64 + nf * 16 + lr;
        if constexpr (BF16OUT)
          ((short*)Cv)[(size_t)row * N + col] = f2b(acc[mf][nf][j]);
        else
          ((float*)Cv)[(size_t)row * N + col] = acc[mf][nf][j];
      }
}

// ---------- fused RoPE + V-transpose (one launch; disjoint data, no ordering dep) ----------
// blocks [0, 4096): RoPE  qkv [B*T][2304] -> qh [B][H][T][128] (q pre-scaled), kh [B][T][128]
// blocks [4096, 4352): V transpose  qkv v-cols -> vt [B][128][T]
#define QSC 0.031879358f
__global__ __launch_bounds__(256) void prep_kernel(const short* __restrict__ qkv,
                                                   const float* __restrict__ cosb,
                                                   const float* __restrict__ sinb,
                                                   short* __restrict__ qh,
                                                   short* __restrict__ kh,
                                                   short* __restrict__ vt) {
  const int tid = threadIdx.x;
  if (blockIdx.x < 4096) {
    const int bt = blockIdx.x;  // b*2048 + t
    const int b = bt >> 11, t = bt & 2047;
    {
      int h = tid >> 4, d0 = (tid & 15) * 8;
      const short* base = qkv + (size_t)bt * 2304 + h * 128;
      bf16x8 qa = *(const bf16x8*)(base + d0);
      int dp = d0 < 64 ? d0 + 64 : d0 - 64;
      bf16x8 qp = *(const bf16x8*)(base + dp);
      const float* cp = cosb + (size_t)bt * 128 + d0;
      const float* sp = sinb + (size_t)bt * 128 + d0;
      float sgn = d0 < 64 ? -1.f : 1.f;
      bf16x8 r;
#pragma unroll
      for (int e = 0; e < 8; ++e)
        r[e] = f2b((b2f(qa[e]) * cp[e] + sgn * b2f(qp[e]) * sp[e]) * QSC);
      *(bf16x8*)(qh + (((size_t)(b * 16 + h) * 2048 + t) * 128 + d0)) = r;
    }
    if (tid < 16) {
      int d0 = tid * 8;
      const short* base = qkv + (size_t)bt * 2304 + 2048;
      bf16x8 ka = *(const bf16x8*)(base + d0);
      int dp = d0 < 64 ? d0 + 64 : d0 - 64;
      bf16x8 kp = *(const bf16x8*)(base + dp);
      const float* cp = cosb + (size_t)bt * 128 + d0;
      const float* sp = sinb + (size_t)bt * 128 + d0;
      float sgn = d0 < 64 ? -1.f : 1.f;
      bf16x8 r;
#pragma unroll
      for (int e = 0; e < 8; ++e)
        r[e] = f2b(b2f(ka[e]) * cp[e] + sgn * b2f(kp[e]) * sp[e]);
      *(bf16x8*)(kh + ((size_t)bt * 128 + d0)) = r;
    }
  } else {
    __shared__ short tile[64][33];
    const int bid = blockIdx.x - 4096;            // 0..255
    const int t0 = (bid & 31) * 64;               // 32 t-tiles
    const int d0 = ((bid >> 5) & 3) * 32;         // 4 d-tiles
    const int b = bid >> 7;                       // 2 batches
    {
      int dl = tid & 31, tl0 = tid >> 5;
#pragma unroll
      for (int r = 0; r < 8; ++r) {
        int tl = tl0 + r * 8;
        tile[tl][dl] = qkv[(size_t)(b * 2048 + t0 + tl) * 2304 + 2176 + d0 + dl];
      }
    }
    __syncthreads();
    {
      int dl = tid >> 3, s0 = (tid & 7) * 8;
      bf16x8 v;
#pragma unroll
      for (int e = 0; e < 8; ++e) v[e] = tile[s0 + e][dl];
      *(bf16x8*)(vt + (size_t)(b * 128 + d0 + dl) * 2048 + t0 + s0) = v;
    }
  }
}

// ---------- causal MQA flash attention v18 (reverted best): 8-wave kv-split ----------
// v16 (KVBLK=128, 17 steps) validated the fixed-cost-per-sync-event model (105->80us).
// v18 adds 2 waves/SIMD at constant work+events (80->66us, verified). v19/v20 showed
// 16 waves (4/SIMD) is infeasible: live set ~148 regs > the 128 cap 4 waves/SIMD
// implies -> unavoidable spill storm. 8 waves with VGPR=116 is the sweet spot.
// 512 threads: wave (wq=wid&3, wp=wid>>2) computes q-strip wq x kv-half wp of each
// 128-kv tile (16 QK + 16 PV MFMA/step). Static-max softmax (Q pre-scaled by
// 1/sqrt(T)*log2e, P = exp2(S)) makes kv-partials additive: once per phase, wp=1
// publishes OT/lacc via K-buffer LDS and wp=0 reduces + stores.
__global__ __launch_bounds__(512) void attn_kernel(const short* __restrict__ qh,
                                                   const short* __restrict__ kh,
                                                   const short* __restrict__ vt,
                                                   short* __restrict__ ao) {
  __shared__ short Ks[2][128 * 128];   // [kv][d] 256B rows, 32KB/buf (also combine scratch)
  __shared__ short Vts[2][128 * 128];  // [d][kv] 256B rows, 32KB/buf (also lacc scratch)
  const int tid = threadIdx.x, lane = tid & 63, wid = tid >> 6;  // wid 0..7
  const int c = lane & 31, hi = lane >> 5;
  const int wq = wid & 3;   // q-strip (32 rows of the 128-q supertile)
  const int wp = wid >> 2;  // kv-half (64 rows of the 128-kv tile)
  const int pi = blockIdx.x;  // 0..7
  const int h = blockIdx.y, b = blockIdx.z;

  // staging: linear LDS dest o = tid*16 + r*8192 (512 thr x 4 rounds x 16B = 32KB);
  // source pre-unswizzled with the involution u = o ^ (((o>>8)&15)<<4).
  int kof[4], vof[4];
#pragma unroll
  for (int r = 0; r < 4; ++r) {
    int o = tid * 16 + r * 8192;
    int u = o ^ (((o >> 8) & 15) << 4);
    kof[r] = u;                            // K: row(kv)*256 + col
    vof[r] = (u >> 8) * 4096 + (u & 255);  // Vt: d = u>>8 (global row 4096B), kv*2
  }
  const char* kgb = (const char*)kh + (size_t)b * 524288;
  const char* vgb = (const char*)vt + (size_t)b * 524288;
  const int ldsu = wid * 1024;  // wave-uniform dest part (lane*16 added by HW)

  auto STAGE = [&](int bufp, int st) {  // st in 128-kv tiles
    char* kd = (char*)Ks[bufp] + ldsu;
    char* vd = (char*)Vts[bufp] + ldsu;
    const char* kgs = kgb + st * 32768;  // s0*256 bytes
    const char* vgs = vgb + st * 256;    // s0*2 bytes
#pragma unroll
    for (int r = 0; r < 4; ++r) load_lds16(kgs + kof[r], kd + r * 8192);
#pragma unroll
    for (int r = 0; r < 4; ++r) load_lds16(vgs + vof[r], vd + r * 8192);
  };

#pragma unroll 1
  for (int ph = 0; ph < 2; ++ph) {
    const int qt = ph ? (15 - pi) : pi;   // 128-q supertile index
    const int q0 = qt * 128 + wq * 32;    // this wave's 32-q strip
    const int qv = q0 + c;
    const int n = qt + 1;                 // 128-kv tiles needed

    if (ph) __syncthreads();  // combine reads of ph=0 done before re-staging

    bf16x8 qf[8];
    const short* qbase = qh + ((size_t)(b * 16 + h) * 2048 + qv) * 128;
#pragma unroll
    for (int ki = 0; ki < 8; ++ki) qf[ki] = *(const bf16x8*)(qbase + ki * 16 + hi * 8);

    f32x16 OT[4];
#pragma unroll
    for (int d = 0; d < 4; ++d) OT[d] = zero16();
    float lacc = 0.f;

    asm volatile("s_waitcnt vmcnt(0)" ::: "memory");  // drain qf loads
    STAGE(0, 0);
    int p = 0;
#pragma unroll 1
    for (int st = 0; st < n; ++st) {
      asm volatile("s_waitcnt vmcnt(0)" ::: "memory");
      barrier_raw();
      if (st + 1 < n) STAGE(p ^ 1, st + 1);

      const char* Ksb = (const char*)Ks[p];
      const char* Vtb = (const char*)Vts[p];
      const bool diag = (st == qt);  // sub-block j (0..3) valid iff j <= wq

      bf16x8 pf[4];  // P fragments for this wave's two 32-kv sub-blocks
#pragma unroll
      for (int jj = 0; jj < 2; ++jj) {
        const int j = wp * 2 + jj;
        if (diag && j > wq) continue;  // wave-uniform skip of fully-masked sub-blocks

        // ---- S = K[32j..32j+31] Q^T ----
        f32x16 S = zero16();
        __builtin_amdgcn_s_setprio(1);
#pragma unroll
        for (int ki = 0; ki < 8; ++ki) {
          int a0 = (32 * j + c) * 256 + ((ki * 32 + hi * 16) ^ ((c & 15) << 4));
          bf16x8 kf = *(const bf16x8*)(Ksb + a0);
          S = mfma32(kf, qf[ki], S);
        }
        __builtin_amdgcn_s_setprio(0);

        // ---- causal mask (only the j == wq sub-block of the diagonal tile) ----
        if (diag && j == wq) {
#pragma unroll
          for (int r = 0; r < 16; ++r) {
            int kvl = (r & 3) + 8 * (r >> 2) + hi * 4;
            S[r] = (kvl > c) ? -1e30f : S[r];
          }
        }

        // ---- P = exp2(S) (static max = 0), per-lane partial row-sum ----
        float ps0 = 0.f, ps1 = 0.f, ps2 = 0.f, ps3 = 0.f;
#pragma unroll
        for (int r = 0; r < 16; r += 4) {
          S[r] = exp2r(S[r]);          ps0 += S[r];
          S[r + 1] = exp2r(S[r + 1]);  ps1 += S[r + 1];
          S[r + 2] = exp2r(S[r + 2]);  ps2 += S[r + 2];
          S[r + 3] = exp2r(S[r + 3]);  ps3 += S[r + 3];
        }
        lacc += (ps0 + ps1) + (ps2 + ps3);

        // ---- pack P -> bf16 + cross-half redistribution (all-VALU) ----
        unsigned D[8];
#pragma unroll
        for (int i = 0; i < 8; ++i) D[i] = pack2(S[2 * i], S[2 * i + 1]);
        unsigned a0 = D[0], a1 = D[1], a2 = D[2], a3 = D[3];
        swap32(a0, a2);
        swap32(a1, a3);
        u32x4 w0;
        w0[0] = a0; w0[1] = a1; w0[2] = a2; w0[3] = a3;
        pf[2 * jj] = __builtin_bit_cast(bf16x8, w0);
        unsigned b0 = D[4], b1 = D[5], b2 = D[6], b3 = D[7];
        swap32(b0, b2);
        swap32(b1, b3);
        u32x4 w1;
        w1[0] = b0; w1[1] = b1; w1[2] = b2; w1[3] = b3;
        pf[2 * jj + 1] = __builtin_bit_cast(bf16x8, w1);
      }

      // ---- O^T += V^T P (this wave's kv-half) ----
      __builtin_amdgcn_s_setprio(1);
#pragma unroll
      for (int dblk = 0; dblk < 4; ++dblk) {
        int rbase = (dblk * 32 + c) * 256;
        int sw = (c & 15) << 4;
#pragma unroll
        for (int jj = 0; jj < 2; ++jj) {
          int j = wp * 2 + jj;
          if (diag && j > wq) continue;
          int av0 = rbase + ((j * 64 + hi * 16) ^ sw);
          bf16x8 vf0 = *(const bf16x8*)(Vtb + av0);
          OT[dblk] = mfma32(vf0, pf[2 * jj], OT[dblk]);
          int av1 = rbase + ((j * 64 + 32 + hi * 16) ^ sw);
          bf16x8 vf1 = *(const bf16x8*)(Vtb + av1);
          OT[dblk] = mfma32(vf1, pf[2 * jj + 1], OT[dblk]);
        }
      }
      __builtin_amdgcn_s_setprio(0);

      p ^= 1;
    }

    // ---- cross-half combine: wp=1 publishes partials; wp=0 reduces + stores ----
    __syncthreads();  // all waves done reading K/V bufs; staging drained (vmcnt0 above)
    float* ob = (float*)Ks + wq * 4096;      // 16KB per strip; 4 strips fill Ks[0..1]
    float* lb = (float*)Vts + wq * 64;       // 64 floats per strip (per-lane partials)
    if (wp == 1) {
#pragma unroll
      for (int dblk = 0; dblk < 4; ++dblk)
#pragma unroll
        for (int rq = 0; rq < 4; ++rq) {
          int off = (lane * 256 + (dblk * 4 + rq) * 16) ^ ((lane & 15) << 4);
          f32x4 piece;
          piece[0] = OT[dblk][4 * rq];
          piece[1] = OT[dblk][4 * rq + 1];
          piece[2] = OT[dblk][4 * rq + 2];
          piece[3] = OT[dblk][4 * rq + 3];
          *(f32x4*)((char*)ob + off) = piece;
        }
      lb[lane] = lacc;
    }
    __syncthreads();
    if (wp == 0) {
#pragma unroll
      for (int dblk = 0; dblk < 4; ++dblk)
#pragma unroll
        for (int rq = 0; rq < 4; ++rq) {
          int off = (lane * 256 + (dblk * 4 + rq) * 16) ^ ((lane & 15) << 4);
          f32x4 piece = *(const f32x4*)((const char*)ob + off);
          OT[dblk][4 * rq] += piece[0];
          OT[dblk][4 * rq + 1] += piece[1];
          OT[dblk][4 * rq + 2] += piece[2];
          OT[dblk][4 * rq + 3] += piece[3];
        }
      float inv = 1.f / xhalfsum(lacc + lb[lane]);

      // epilogue: O^T / lsum -> ao[b][q][h][d], paired-d dword stores
      short* aob = ao + ((size_t)(b * 2048 + qv) * 2048 + h * 128);
#pragma unroll
      for (int dblk = 0; dblk < 4; ++dblk) {
#pragma unroll
        for (int rp = 0; rp < 8; ++rp) {
          int r = rp * 2;
          int dd = dblk * 32 + (r & 3) + 8 * (r >> 2) + hi * 4;
          unsigned w = pack2(OT[dblk][r] * inv, OT[dblk][r + 1] * inv);
          *(unsigned*)(aob + dd) = w;
        }
      }
    }
  }
}

// ---------- launch ----------
extern "C" void kernel_launch(void* const* d_in, const int* in_sizes, int n_in,
                              void* d_out, int out_size, void* d_ws, size_t ws_size,
                              hipStream_t stream) {
  const float* x = (const float*)d_in[0];
  const float* cosb = (const float*)d_in[1];
  const float* sinb = (const float*)d_in[2];
  const float* Wq = (const float*)d_in[3];
  const float* Wk = (const float*)d_in[4];
  const float* Wv = (const float*)d_in[5];
  const float* Wo = (const float*)d_in[6];

  char* ws = (char*)d_ws;
  short* xb = (short*)(ws);                    // 16.78 MB  (aliased as ao later)
  short* wcat = (short*)(ws + 16777216);       // 9.44 MB
  short* wob = (short*)(ws + 26214400);        // 8.39 MB
  short* qkv = (short*)(ws + 34603008);        // 18.87 MB
  short* qh = (short*)(ws + 53477376);         // 16.78 MB
  short* kh = (short*)(ws + 70254592);         // 1.05 MB
  short* vt = (short*)(ws + 71303168);         // 1.05 MB
  short* ao = xb;                              // xb dead after gemm1

  cvt_all_kernel<<<8448, 256, 0, stream>>>(x, Wq, Wk, Wv, Wo, xb, wcat, wob);

  gemm_nt<1><<<576, 256, 0, stream>>>(xb, wcat, qkv, 4096, 2304, 2048);
  prep_kernel<<<4352, 256, 0, stream>>>(qkv, cosb, sinb, qh, kh, vt);
  attn_kernel<<<dim3(8, 16, 2), 512, 0, stream>>>(qh, kh, vt, ao);
  gemm_nt<0><<<512, 256, 0, stream>>>(ao, wob, d_out, 4096, 2048, 2048);
}